// Round 2
// baseline (82.171 us; speedup 1.0000x reference)
//
#include <hip/hip_runtime.h>

// FastFocalLoss: scalar = -(pos_loss + neg_loss)/num_pos  (or -neg_loss if no pos)
//   neg_loss = sum log(1-o) * o^2 * (1-t)^4     over all elements
//   pos_loss = sum_{t==1} log(o) * (1-o)^2
//   num_pos  = count(t == 1.0)
// VALU-bound (R1 post-mortem): f32 inner accumulation (error budget huge:
// absmax 0.0 vs thr 2.27 with f64), 32-bit indexing, unroll-4. Double only
// in the cross-lane/cross-block reduction.

__device__ __forceinline__ double wave_reduce_add(double v) {
    #pragma unroll
    for (int off = 32; off > 0; off >>= 1) v += __shfl_down(v, off, 64);
    return v;
}

// Block-level reduce of three doubles (256 threads = 4 waves).
__device__ __forceinline__ void block_reduce3(double& neg, double& pos, double& cnt) {
    __shared__ double s_neg[4], s_pos[4], s_cnt[4];
    neg = wave_reduce_add(neg);
    pos = wave_reduce_add(pos);
    cnt = wave_reduce_add(cnt);
    const int lane = threadIdx.x & 63;
    const int wid  = threadIdx.x >> 6;
    if (lane == 0) { s_neg[wid] = neg; s_pos[wid] = pos; s_cnt[wid] = cnt; }
    __syncthreads();
    if (wid == 0) {
        neg = (lane < 4) ? s_neg[lane] : 0.0;
        pos = (lane < 4) ? s_pos[lane] : 0.0;
        cnt = (lane < 4) ? s_cnt[lane] : 0.0;
        #pragma unroll
        for (int off = 2; off > 0; off >>= 1) {
            neg += __shfl_down(neg, off, 0);
            pos += __shfl_down(pos, off, 0);
            cnt += __shfl_down(cnt, off, 0);
        }
    }
}

__device__ __forceinline__ void accum_elem(float o, float t,
                                           float& neg, float& pos, int& cnt) {
    float g  = 1.0f - t;
    float g2 = g * g;
    neg += __logf(1.0f - o) * (o * o) * (g2 * g2);
    if (t == 1.0f) {
        float io = 1.0f - o;
        pos += __logf(o) * io * io;
        cnt += 1;
    }
}

__global__ __launch_bounds__(256)
void ffl_partial(const float4* __restrict__ out4, const float4* __restrict__ tgt4,
                 int n4,
                 const float* __restrict__ out_s, const float* __restrict__ tgt_s,
                 int tail_start, int n,
                 double* __restrict__ ws) {
    float negf = 0.0f, posf = 0.0f;
    int cnt = 0;
    const int idx    = blockIdx.x * 256 + threadIdx.x;
    const int stride = gridDim.x * 256;

    #pragma unroll 4
    for (int i = idx; i < n4; i += stride) {
        float4 o = out4[i];
        float4 t = tgt4[i];
        accum_elem(o.x, t.x, negf, posf, cnt);
        accum_elem(o.y, t.y, negf, posf, cnt);
        accum_elem(o.z, t.z, negf, posf, cnt);
        accum_elem(o.w, t.w, negf, posf, cnt);
    }
    // scalar tail (n not divisible by 4)
    for (int i = tail_start + idx; i < n; i += stride) {
        accum_elem(out_s[i], tgt_s[i], negf, posf, cnt);
    }

    double neg = (double)negf, pos = (double)posf, c = (double)cnt;
    block_reduce3(neg, pos, c);
    if (threadIdx.x == 0) {
        ws[3 * blockIdx.x + 0] = neg;
        ws[3 * blockIdx.x + 1] = pos;
        ws[3 * blockIdx.x + 2] = c;
    }
}

__global__ __launch_bounds__(256)
void ffl_final(const double* __restrict__ ws, int nparts, float* __restrict__ out) {
    double neg = 0.0, pos = 0.0, cnt = 0.0;
    for (int i = threadIdx.x; i < nparts; i += 256) {
        neg += ws[3 * i + 0];
        pos += ws[3 * i + 1];
        cnt += ws[3 * i + 2];
    }
    block_reduce3(neg, pos, cnt);
    if (threadIdx.x == 0) {
        double r = (cnt == 0.0) ? (-neg) : (-(pos + neg) / cnt);
        out[0] = (float)r;
    }
}

extern "C" void kernel_launch(void* const* d_in, const int* in_sizes, int n_in,
                              void* d_out, int out_size, void* d_ws, size_t ws_size,
                              hipStream_t stream) {
    const float* outp = (const float*)d_in[0];
    const float* tgtp = (const float*)d_in[1];
    const int n  = in_sizes[0];
    const int n4 = n >> 2;            // float4 count
    const int tail_start = n4 << 2;

    double* ws = (double*)d_ws;
    int blocks = 2048;                 // 8 blocks/CU at 256 thr = full occupancy
    const int max_blocks = (int)(ws_size / (3 * sizeof(double)));
    if (blocks > max_blocks) blocks = max_blocks;
    if (blocks < 1) blocks = 1;

    ffl_partial<<<blocks, 256, 0, stream>>>(
        (const float4*)outp, (const float4*)tgtp, n4,
        outp, tgtp, tail_start, n, ws);
    ffl_final<<<1, 256, 0, stream>>>(ws, blocks, (float*)d_out);
}

// Round 3
// 80.939 us; speedup vs baseline: 1.0152x; 1.0152x over previous
//
#include <hip/hip_runtime.h>

// FastFocalLoss: scalar = -(pos_loss + neg_loss)/num_pos  (or -neg_loss if no pos)
//   neg_loss = sum log(1-o) * o^2 * (1-t)^4     over all elements
//   pos_loss = sum_{t==1} log(o) * (1-o)^2
//   num_pos  = count(t == 1.0)
// R2 post-mortem: latency/MLP-bound (VGPR=28 => only ~2 loads in flight).
// Fix: block-contiguous chunks + manual 4-stripe load batching (8 dwordx4
// outstanding, named regs = static indexing), f32 inner accum.

__device__ __forceinline__ double wave_reduce_add(double v) {
    #pragma unroll
    for (int off = 32; off > 0; off >>= 1) v += __shfl_down(v, off, 64);
    return v;
}

// Block-level reduce of three doubles (256 threads = 4 waves).
__device__ __forceinline__ void block_reduce3(double& neg, double& pos, double& cnt) {
    __shared__ double s_neg[4], s_pos[4], s_cnt[4];
    neg = wave_reduce_add(neg);
    pos = wave_reduce_add(pos);
    cnt = wave_reduce_add(cnt);
    const int lane = threadIdx.x & 63;
    const int wid  = threadIdx.x >> 6;
    if (lane == 0) { s_neg[wid] = neg; s_pos[wid] = pos; s_cnt[wid] = cnt; }
    __syncthreads();
    if (wid == 0) {
        neg = (lane < 4) ? s_neg[lane] : 0.0;
        pos = (lane < 4) ? s_pos[lane] : 0.0;
        cnt = (lane < 4) ? s_cnt[lane] : 0.0;
        #pragma unroll
        for (int off = 2; off > 0; off >>= 1) {
            neg += __shfl_down(neg, off, 64);
            pos += __shfl_down(pos, off, 64);
            cnt += __shfl_down(cnt, off, 64);
        }
    }
}

__device__ __forceinline__ void accum_elem(float o, float t,
                                           float& neg, float& pos, int& cnt) {
    float g  = 1.0f - t;
    float g2 = g * g;
    neg += __logf(1.0f - o) * (o * o) * (g2 * g2);
    if (t == 1.0f) {
        float io = 1.0f - o;
        pos += __logf(o) * io * io;
        cnt += 1;
    }
}

__device__ __forceinline__ void accum4(const float4 o, const float4 t,
                                       float& neg, float& pos, int& cnt) {
    accum_elem(o.x, t.x, neg, pos, cnt);
    accum_elem(o.y, t.y, neg, pos, cnt);
    accum_elem(o.z, t.z, neg, pos, cnt);
    accum_elem(o.w, t.w, neg, pos, cnt);
}

__global__ __launch_bounds__(256)
void ffl_partial(const float4* __restrict__ out4, const float4* __restrict__ tgt4,
                 int n4,
                 const float* __restrict__ out_s, const float* __restrict__ tgt_s,
                 int tail_start, int n,
                 double* __restrict__ ws) {
    float negf = 0.0f, posf = 0.0f;
    int cnt = 0;

    // Block-contiguous chunk: block b owns [b*chunk, min((b+1)*chunk, n4)).
    const int chunk = (n4 + gridDim.x - 1) / gridDim.x;
    const int start = blockIdx.x * chunk;
    const int end   = min(start + chunk, n4);

    int i = start + (int)threadIdx.x;
    // Main loop: 4 stripes of 256 float4 each -> 8 dwordx4 loads in flight.
    for (; i + 768 < end; i += 1024) {
        float4 o0 = out4[i];
        float4 t0 = tgt4[i];
        float4 o1 = out4[i + 256];
        float4 t1 = tgt4[i + 256];
        float4 o2 = out4[i + 512];
        float4 t2 = tgt4[i + 512];
        float4 o3 = out4[i + 768];
        float4 t3 = tgt4[i + 768];
        accum4(o0, t0, negf, posf, cnt);
        accum4(o1, t1, negf, posf, cnt);
        accum4(o2, t2, negf, posf, cnt);
        accum4(o3, t3, negf, posf, cnt);
    }
    // Remainder stripes within the chunk.
    for (; i < end; i += 256) {
        accum4(out4[i], tgt4[i], negf, posf, cnt);
    }
    // Scalar tail (n not divisible by 4) — grid-level.
    for (int j = tail_start + blockIdx.x * 256 + (int)threadIdx.x; j < n;
         j += gridDim.x * 256) {
        accum_elem(out_s[j], tgt_s[j], negf, posf, cnt);
    }

    double neg = (double)negf, pos = (double)posf, c = (double)cnt;
    block_reduce3(neg, pos, c);
    if (threadIdx.x == 0) {
        ws[3 * blockIdx.x + 0] = neg;
        ws[3 * blockIdx.x + 1] = pos;
        ws[3 * blockIdx.x + 2] = c;
    }
}

__global__ __launch_bounds__(256)
void ffl_final(const double* __restrict__ ws, int nparts, float* __restrict__ out) {
    double neg = 0.0, pos = 0.0, cnt = 0.0;
    for (int i = threadIdx.x; i < nparts; i += 256) {
        neg += ws[3 * i + 0];
        pos += ws[3 * i + 1];
        cnt += ws[3 * i + 2];
    }
    block_reduce3(neg, pos, cnt);
    if (threadIdx.x == 0) {
        double r = (cnt == 0.0) ? (-neg) : (-(pos + neg) / cnt);
        out[0] = (float)r;
    }
}

extern "C" void kernel_launch(void* const* d_in, const int* in_sizes, int n_in,
                              void* d_out, int out_size, void* d_ws, size_t ws_size,
                              hipStream_t stream) {
    const float* outp = (const float*)d_in[0];
    const float* tgtp = (const float*)d_in[1];
    const int n  = in_sizes[0];
    const int n4 = n >> 2;            // float4 count
    const int tail_start = n4 << 2;

    double* ws = (double*)d_ws;
    int blocks = 2048;                 // 8 blocks/CU at 256 thr
    const int max_blocks = (int)(ws_size / (3 * sizeof(double)));
    if (blocks > max_blocks) blocks = max_blocks;
    if (blocks < 1) blocks = 1;

    ffl_partial<<<blocks, 256, 0, stream>>>(
        (const float4*)outp, (const float4*)tgtp, n4,
        outp, tgtp, tail_start, n, ws);
    ffl_final<<<1, 256, 0, stream>>>(ws, blocks, (float*)d_out);
}

// Round 4
// 78.987 us; speedup vs baseline: 1.0403x; 1.0247x over previous
//
#include <hip/hip_runtime.h>

// FastFocalLoss: scalar = -(pos_loss + neg_loss)/num_pos  (or -neg_loss if no pos)
//   neg_loss = sum log(1-o) * o^2 * (1-t)^4     over all elements
//   pos_loss = sum_{t==1} log(o) * (1-o)^2
//   num_pos  = count(t == 1.0)
// R3 post-mortem: compiler pins VGPR=28 and serializes loads (~2 KB/wave in
// flight) regardless of source-level batching. Force 8 KB/wave MLP via inline
// asm: 8x global_load_dwordx4 per iteration, counted vmcnt(6/4/2/0) waits,
// sched_barrier(0) after each wait (rule #18: FP compute isn't ordered by
// "memory" clobber alone).

typedef __attribute__((ext_vector_type(4))) float f32x4;

__device__ __forceinline__ double wave_reduce_add(double v) {
    #pragma unroll
    for (int off = 32; off > 0; off >>= 1) v += __shfl_down(v, off, 64);
    return v;
}

__device__ __forceinline__ void block_reduce3(double& neg, double& pos, double& cnt) {
    __shared__ double s_neg[4], s_pos[4], s_cnt[4];
    neg = wave_reduce_add(neg);
    pos = wave_reduce_add(pos);
    cnt = wave_reduce_add(cnt);
    const int lane = threadIdx.x & 63;
    const int wid  = threadIdx.x >> 6;
    if (lane == 0) { s_neg[wid] = neg; s_pos[wid] = pos; s_cnt[wid] = cnt; }
    __syncthreads();
    if (wid == 0) {
        neg = (lane < 4) ? s_neg[lane] : 0.0;
        pos = (lane < 4) ? s_pos[lane] : 0.0;
        cnt = (lane < 4) ? s_cnt[lane] : 0.0;
        #pragma unroll
        for (int off = 2; off > 0; off >>= 1) {
            neg += __shfl_down(neg, off, 64);
            pos += __shfl_down(pos, off, 64);
            cnt += __shfl_down(cnt, off, 64);
        }
    }
}

__device__ __forceinline__ void accum_elem(float o, float t,
                                           float& neg, float& pos, int& cnt) {
    float g  = 1.0f - t;
    float g2 = g * g;
    neg += __logf(1.0f - o) * (o * o) * (g2 * g2);
    if (t == 1.0f) {
        float io = 1.0f - o;
        pos += __logf(o) * io * io;
        cnt += 1;
    }
}

__device__ __forceinline__ void accum4(const f32x4 o, const f32x4 t,
                                       float& neg, float& pos, int& cnt) {
    accum_elem(o.x, t.x, neg, pos, cnt);
    accum_elem(o.y, t.y, neg, pos, cnt);
    accum_elem(o.z, t.z, neg, pos, cnt);
    accum_elem(o.w, t.w, neg, pos, cnt);
}

__global__ __launch_bounds__(256)
void ffl_partial(const f32x4* __restrict__ out4, const f32x4* __restrict__ tgt4,
                 int n4,
                 const float* __restrict__ out_s, const float* __restrict__ tgt_s,
                 int tail_start, int n,
                 double* __restrict__ ws) {
    float negf = 0.0f, posf = 0.0f;
    int cnt = 0;

    // Block-contiguous chunk of float4s.
    const int chunk = (n4 + (int)gridDim.x - 1) / (int)gridDim.x;
    const int start = (int)blockIdx.x * chunk;
    const int end   = min(start + chunk, n4);
    const int span  = end - start;
    const int nfull = span / 1024;     // full iterations: 256 thr x 4 f4

    int base = start;
    for (int it = 0; it < nfull; ++it, base += 1024) {
        const int i = base + 4 * (int)threadIdx.x;   // 64B chunk per thread
        const f32x4* po = out4 + i;
        const f32x4* pt = tgt4 + i;
        f32x4 o0, o1, o2, o3, t0, t1, t2, t3;
        asm volatile(
            "global_load_dwordx4 %0, %[po], off\n\t"
            "global_load_dwordx4 %4, %[pt], off\n\t"
            "global_load_dwordx4 %1, %[po], off offset:16\n\t"
            "global_load_dwordx4 %5, %[pt], off offset:16\n\t"
            "global_load_dwordx4 %2, %[po], off offset:32\n\t"
            "global_load_dwordx4 %6, %[pt], off offset:32\n\t"
            "global_load_dwordx4 %3, %[po], off offset:48\n\t"
            "global_load_dwordx4 %7, %[pt], off offset:48"
            : "=&v"(o0), "=&v"(o1), "=&v"(o2), "=&v"(o3),
              "=&v"(t0), "=&v"(t1), "=&v"(t2), "=&v"(t3)
            : [po] "v"(po), [pt] "v"(pt)
            : "memory");

        asm volatile("s_waitcnt vmcnt(6)" ::: "memory");
        __builtin_amdgcn_sched_barrier(0);
        accum4(o0, t0, negf, posf, cnt);

        asm volatile("s_waitcnt vmcnt(4)" ::: "memory");
        __builtin_amdgcn_sched_barrier(0);
        accum4(o1, t1, negf, posf, cnt);

        asm volatile("s_waitcnt vmcnt(2)" ::: "memory");
        __builtin_amdgcn_sched_barrier(0);
        accum4(o2, t2, negf, posf, cnt);

        asm volatile("s_waitcnt vmcnt(0)" ::: "memory");
        __builtin_amdgcn_sched_barrier(0);
        accum4(o3, t3, negf, posf, cnt);
    }

    // Remainder float4s within the chunk (plain code; compiler inserts waits).
    for (int i = base + (int)threadIdx.x; i < end; i += 256) {
        accum4(out4[i], tgt4[i], negf, posf, cnt);
    }
    // Scalar tail (n not divisible by 4) — grid-level.
    for (int j = tail_start + (int)blockIdx.x * 256 + (int)threadIdx.x; j < n;
         j += (int)gridDim.x * 256) {
        accum_elem(out_s[j], tgt_s[j], negf, posf, cnt);
    }

    double neg = (double)negf, pos = (double)posf, c = (double)cnt;
    block_reduce3(neg, pos, c);
    if (threadIdx.x == 0) {
        ws[3 * blockIdx.x + 0] = neg;
        ws[3 * blockIdx.x + 1] = pos;
        ws[3 * blockIdx.x + 2] = c;
    }
}

__global__ __launch_bounds__(256)
void ffl_final(const double* __restrict__ ws, int nparts, float* __restrict__ out) {
    double neg = 0.0, pos = 0.0, cnt = 0.0;
    for (int i = threadIdx.x; i < nparts; i += 256) {
        neg += ws[3 * i + 0];
        pos += ws[3 * i + 1];
        cnt += ws[3 * i + 2];
    }
    block_reduce3(neg, pos, cnt);
    if (threadIdx.x == 0) {
        double r = (cnt == 0.0) ? (-neg) : (-(pos + neg) / cnt);
        out[0] = (float)r;
    }
}

extern "C" void kernel_launch(void* const* d_in, const int* in_sizes, int n_in,
                              void* d_out, int out_size, void* d_ws, size_t ws_size,
                              hipStream_t stream) {
    const float* outp = (const float*)d_in[0];
    const float* tgtp = (const float*)d_in[1];
    const int n  = in_sizes[0];
    const int n4 = n >> 2;            // float4 count
    const int tail_start = n4 << 2;

    double* ws = (double*)d_ws;
    int blocks = 2048;                 // 2048 x 6144 f4 = exactly n4 (6 full iters)
    const int max_blocks = (int)(ws_size / (3 * sizeof(double)));
    if (blocks > max_blocks) blocks = max_blocks;
    if (blocks < 1) blocks = 1;

    ffl_partial<<<blocks, 256, 0, stream>>>(
        (const f32x4*)outp, (const f32x4*)tgtp, n4,
        outp, tgtp, tail_start, n, ws);
    ffl_final<<<1, 256, 0, stream>>>(ws, blocks, (float*)d_out);
}